// Round 1
// 632.479 us; speedup vs baseline: 1.1238x; 1.1238x over previous
//
#include <hip/hip_runtime.h>

typedef __bf16 bf16;
typedef __attribute__((ext_vector_type(8))) __bf16 bf16x8;
typedef __attribute__((ext_vector_type(4))) float f32x4;

#define MFMA16(a, b, c) __builtin_amdgcn_mfma_f32_16x16x32_bf16(a, b, c, 0, 0, 0)

constexpr int XS = 136;   // XO row stride (bf16): 272 B, 16B-aligned rows
constexpr int PSS = 40;   // per-wave slice row stride (bf16): 80 B, 16B-aligned rows
constexpr float SCALE = 0.08838834764831845f;  // C^-0.5

// ---------------- weight prepack: 128 frags x 1 KiB ----------------
//  f in [ 0,32): A-frags of Wq^T (pre-scaled): id = h*8 + mt*4 + ks
//                lane: Wq[c=ks*32+quad*8+j][d=mt*16+c16]
//  f in [32,64): A-frags of Wk^T: id = 32 + h*8 + mt*4 + ks
//  f in [64,96): B-frags of Wv:   id = 64 + h*8 + nt*4 + ks
//                lane: Wv[c=ks*32+quad*8+j][d=nt*16+c16]
//  f in [96,128): B-frags of Wp^T: id = 96 + nt*4 + kt (kt = head slice of k)
__global__ void prepack(const float* __restrict__ Wq, const float* __restrict__ Wk,
                        const float* __restrict__ Wv, const float* __restrict__ Wp,
                        uint4* __restrict__ frags) {
  int tid = blockIdx.x * blockDim.x + threadIdx.x;   // 8192 threads
  int f = tid >> 6, lane = tid & 63, quad = lane >> 4, c16 = lane & 15;
  union { bf16 e[8]; uint4 v; } o;
  if (f < 64) {
    int isK = f >> 5, g = f & 31, h = g >> 3, mt = (g >> 2) & 1, ks = g & 3;
    const float* W = isK ? Wk : Wq;
    const float* src = W + h * 4096 + (ks * 32 + quad * 8) * 32 + mt * 16 + c16;
    float sc = isK ? 1.f : SCALE;
#pragma unroll
    for (int j = 0; j < 8; ++j) o.e[j] = (bf16)(src[j * 32] * sc);
  } else if (f < 96) {
    int g = f - 64, h = g >> 3, nt = (g >> 2) & 1, ks = g & 3;
    const float* src = Wv + h * 4096 + (ks * 32 + quad * 8) * 32 + nt * 16 + c16;
#pragma unroll
    for (int j = 0; j < 8; ++j) o.e[j] = (bf16)src[j * 32];
  } else {
    int g = f - 96, nt = g >> 2, kt = g & 3;
    const float* src = Wp + (nt * 16 + c16) * 128 + kt * 32 + quad * 8;
#pragma unroll
    for (int j = 0; j < 8; ++j) o.e[j] = (bf16)src[j];
  }
  frags[f * 64 + lane] = o.v;
}

__device__ __forceinline__ uint2 pack4(f32x4 a) {
  union { bf16 e[4]; uint2 u; } p;
#pragma unroll
  for (int r = 0; r < 4; ++r) p.e[r] = (bf16)a[r];
  return p.u;
}

// ---------------- fused MHA: 1 block = 1 batch, 4 waves, 1 wave = 1 head ----------------
// 3 barriers total; Q/K/V operand fragments live in registers; attention barrier-free.
__global__ __launch_bounds__(256, 4) void mha4(
    const float* __restrict__ x, const bf16* __restrict__ fr,
    const float* __restrict__ bp, float* __restrict__ out) {
  __shared__ __align__(16) bf16 XO[128 * XS];      // x (bf16) -> later O[t][hd] -> Y f32 scratch
  __shared__ __align__(16) bf16 PS[4][16 * PSS];   // per-wave transpose slice (16 x 32 used)

  const int b = blockIdx.x, tid = threadIdx.x;
  const int w = tid >> 6, lane = tid & 63, quad = lane >> 4, c16 = lane & 15;
  const bf16x8* frv = (const bf16x8*)fr;
  bf16* ps = PS[w];

  float bias[8];
#pragma unroll
  for (int nt = 0; nt < 8; ++nt) bias[nt] = bp[nt * 16 + c16];

  // ---- phase 0: stage x as bf16 into XO (coalesced float4 loads) ----
  const float* xb = x + (size_t)b * 16384;
#pragma unroll
  for (int i = 0; i < 16; ++i) {
    int idx = tid + i * 256, row = idx >> 5, f4 = idx & 31;
    float4 a = *(const float4*)(xb + idx * 4);
    union { bf16 e[4]; uint2 u; } pk;
    pk.e[0] = (bf16)a.x; pk.e[1] = (bf16)a.y; pk.e[2] = (bf16)a.z; pk.e[3] = (bf16)a.w;
    *(uint2*)&XO[row * XS + f4 * 4] = pk.u;
  }
  __syncthreads();   // #1

  // ---- phase 1: projections for head h = w; end with qf/kf/vf in registers ----
  // qf[m]: lane = Q[t=m*16+c16][d=quad*8+j]      (B-frag of Q^T)
  // kf[nt]: lane = K[s=nt*16+c16][d=quad*8+j]    (A-frag)
  // vf[dt][kc]: lane = V^T[d=dt*16+c16][s=kc*32+quad*8+j] (A-frag)
  bf16x8 qf[8], kf[8], vf[2][4];
  {
    bf16x8 wq[2][4], wk[2][4];
#pragma unroll
    for (int mt = 0; mt < 2; ++mt)
#pragma unroll
      for (int ks = 0; ks < 4; ++ks) {
        wq[mt][ks] = frv[(w * 8 + mt * 4 + ks) * 64 + lane];
        wk[mt][ks] = frv[(32 + w * 8 + mt * 4 + ks) * 64 + lane];
      }
#pragma unroll
    for (int tt = 0; tt < 8; ++tt) {
      bf16x8 xa[4];
#pragma unroll
      for (int ks = 0; ks < 4; ++ks)
        xa[ks] = *(const bf16x8*)&XO[(tt * 16 + c16) * XS + ks * 32 + quad * 8];
      f32x4 q0 = {0,0,0,0}, q1 = {0,0,0,0}, k0 = {0,0,0,0}, k1 = {0,0,0,0};
#pragma unroll
      for (int ks = 0; ks < 4; ++ks) {
        q0 = MFMA16(wq[0][ks], xa[ks], q0);   // Q^T = Wq^T x^T : C row=d, col=t
        q1 = MFMA16(wq[1][ks], xa[ks], q1);
        k0 = MFMA16(wk[0][ks], xa[ks], k0);
        k1 = MFMA16(wk[1][ks], xa[ks], k1);
      }
      // transpose via wave-private slice: write [t=c16][d], read b128 -> operand frag
      *(uint2*)&ps[c16 * PSS + quad * 4] = pack4(q0);
      *(uint2*)&ps[c16 * PSS + 16 + quad * 4] = pack4(q1);
      qf[tt] = *(const bf16x8*)&ps[c16 * PSS + quad * 8];
      *(uint2*)&ps[c16 * PSS + quad * 4] = pack4(k0);
      *(uint2*)&ps[c16 * PSS + 16 + quad * 4] = pack4(k1);
      kf[tt] = *(const bf16x8*)&ps[c16 * PSS + quad * 8];
    }
    bf16x8 wv[2][4];
#pragma unroll
    for (int nt = 0; nt < 2; ++nt)
#pragma unroll
      for (int ks = 0; ks < 4; ++ks)
        wv[nt][ks] = frv[(64 + w * 8 + nt * 4 + ks) * 64 + lane];
    uint2 vp[2][2];
#pragma unroll
    for (int tt = 0; tt < 8; ++tt) {
      bf16x8 xa[4];
#pragma unroll
      for (int ks = 0; ks < 4; ++ks)
        xa[ks] = *(const bf16x8*)&XO[(tt * 16 + c16) * XS + ks * 32 + quad * 8];
      f32x4 v0 = {0,0,0,0}, v1 = {0,0,0,0};
#pragma unroll
      for (int ks = 0; ks < 4; ++ks) {
        v0 = MFMA16(xa[ks], wv[0][ks], v0);   // V = x Wv : C row=s, col=d
        v1 = MFMA16(xa[ks], wv[1][ks], v1);
      }
      vp[0][tt & 1] = pack4(v0);
      vp[1][tt & 1] = pack4(v1);
      if (tt & 1) {
        const int kc = tt >> 1;
#pragma unroll
        for (int dt = 0; dt < 2; ++dt) {
          *(uint2*)&ps[c16 * PSS + quad * 4] = vp[dt][0];       // [d=c16][s 0..15]
          *(uint2*)&ps[c16 * PSS + 16 + quad * 4] = vp[dt][1];  // [d=c16][s 16..31]
          vf[dt][kc] = *(const bf16x8*)&ps[c16 * PSS + quad * 8];
        }
      }
    }
  }
  __syncthreads();   // #2 — all x reads done; XO becomes O[t][hd]

  // ---- phase 2: attention, fully wave-independent ----
#pragma unroll
  for (int m = 0; m < 8; ++m) {
    f32x4 st[8];
#pragma unroll
    for (int nt = 0; nt < 8; ++nt) {
      if (nt <= m) {
        f32x4 z = {0,0,0,0};
        st[nt] = MFMA16(kf[nt], qf[m], z);   // S^T: lane col t = m*16+c16, rows s = nt*16+quad*4+r
      }
    }
    float mx = -1e30f;
#pragma unroll
    for (int nt = 0; nt < 8; ++nt) {
      if (nt < m) {
#pragma unroll
        for (int r = 0; r < 4; ++r) mx = fmaxf(mx, st[nt][r]);
      } else if (nt == m) {
#pragma unroll
        for (int r = 0; r < 4; ++r) {
          float v = (quad * 4 + r > c16) ? -1e30f : st[nt][r];
          st[nt][r] = v;
          mx = fmaxf(mx, v);
        }
      }
    }
    mx = fmaxf(mx, __shfl_xor(mx, 16));
    mx = fmaxf(mx, __shfl_xor(mx, 32));
    float sum = 0.f;
#pragma unroll
    for (int nt = 0; nt < 8; ++nt) {
      if (nt <= m) {
#pragma unroll
        for (int r = 0; r < 4; ++r) {
          float e = __expf(st[nt][r] - mx);
          st[nt][r] = e;
          sum += e;
        }
      }
    }
    sum += __shfl_xor(sum, 16);
    sum += __shfl_xor(sum, 32);
    const float inv = __builtin_amdgcn_rcpf(sum);

    f32x4 oa0 = {0,0,0,0}, oa1 = {0,0,0,0};
#pragma unroll
    for (int kc = 0; kc < 4; ++kc) {
      if (kc <= (m >> 1)) {
#pragma unroll
        for (int n2 = 0; n2 < 2; ++n2) {
          const int nt = kc * 2 + n2;
          uint2 p;
          if (nt <= m) p = pack4(st[nt]);
          else { p.x = 0u; p.y = 0u; }
          *(uint2*)&ps[c16 * PSS + n2 * 16 + quad * 4] = p;
        }
        bf16x8 pf = *(const bf16x8*)&ps[c16 * PSS + quad * 8];
        oa0 = MFMA16(vf[0][kc], pf, oa0);
        oa1 = MFMA16(vf[1][kc], pf, oa1);
      }
    }
    // stage O (normalized) into XO[t][hd] at this wave's column stripe
    union { bf16 e[4]; uint2 u; } q0, q1;
#pragma unroll
    for (int r = 0; r < 4; ++r) {
      q0.e[r] = (bf16)(oa0[r] * inv);
      q1.e[r] = (bf16)(oa1[r] * inv);
    }
    *(uint2*)&XO[(m * 16 + c16) * XS + w * 32 + quad * 4] = q0.u;
    *(uint2*)&XO[(m * 16 + c16) * XS + w * 32 + 16 + quad * 4] = q1.u;
  }
  __syncthreads();   // #3 — O complete

  // ---- phase 3: Y = O Wp^T + b ; wave w owns rows w*32..w*32+31 ----
  f32x4 yacc[2][8];
#pragma unroll
  for (int rb = 0; rb < 2; ++rb)
#pragma unroll
    for (int nt = 0; nt < 8; ++nt) yacc[rb][nt] = (f32x4){0,0,0,0};
#pragma unroll
  for (int rb = 0; rb < 2; ++rb) {
    bf16x8 of[4];
#pragma unroll
    for (int kt = 0; kt < 4; ++kt)
      of[kt] = *(const bf16x8*)&XO[(w * 32 + rb * 16 + c16) * XS + kt * 32 + quad * 8];
#pragma unroll
    for (int nt = 0; nt < 8; ++nt)
#pragma unroll
      for (int kt = 0; kt < 4; ++kt)
        yacc[rb][nt] = MFMA16(of[kt], frv[(96 + nt * 4 + kt) * 64 + lane], yacc[rb][nt]);
  }

  // ---- epilogue: per-wave LDS transpose -> full-line float4 stores ----
  float* YS = (float*)&XO[(w * 32) * XS];   // 8704 B wave-private region, stride 132 f32
  float* ob = out + (size_t)b * 16384 + (w * 32) * 128;
#pragma unroll
  for (int p = 0; p < 2; ++p) {
#pragma unroll
    for (int nt = 0; nt < 8; ++nt)
#pragma unroll
      for (int r = 0; r < 4; ++r)
        YS[(quad * 4 + r) * 132 + nt * 16 + c16] = yacc[p][nt][r] + bias[nt];
#pragma unroll
    for (int si = 0; si < 8; ++si) {
      const int row = (lane >> 5) + si * 2;
      *(float4*)&ob[(p * 16 + row) * 128 + (lane & 31) * 4] =
          *(const float4*)&YS[row * 132 + (lane & 31) * 4];
    }
  }
}

extern "C" void kernel_launch(void* const* d_in, const int* in_sizes, int n_in,
                              void* d_out, int out_size, void* d_ws, size_t ws_size,
                              hipStream_t stream) {
  (void)in_sizes; (void)n_in; (void)out_size; (void)ws_size;
  const float* x  = (const float*)d_in[0];
  const float* Wq = (const float*)d_in[1];
  const float* Wk = (const float*)d_in[2];
  const float* Wv = (const float*)d_in[3];
  const float* Wp = (const float*)d_in[4];
  const float* bp = (const float*)d_in[5];
  bf16* frags = (bf16*)d_ws;   // 128 frags * 1 KiB = 128 KiB
  prepack<<<dim3(32), dim3(256), 0, stream>>>(Wq, Wk, Wv, Wp, (uint4*)frags);
  mha4<<<dim3(4096), dim3(256), 0, stream>>>(x, frags, bp, (float*)d_out);
}

// Round 2
// 494.252 us; speedup vs baseline: 1.4380x; 1.2797x over previous
//
#include <hip/hip_runtime.h>

typedef __bf16 bf16;
typedef __attribute__((ext_vector_type(8))) __bf16 bf16x8;
typedef __attribute__((ext_vector_type(4))) float f32x4;

#define MFMA16(a, b, c) __builtin_amdgcn_mfma_f32_16x16x32_bf16(a, b, c, 0, 0, 0)

constexpr int XS = 136;   // XO row stride (bf16): 272 B, 16B-aligned rows
constexpr int PSS = 40;   // per-wave slice row stride (bf16): 80 B, 16B-aligned rows
constexpr float SCALE = 0.08838834764831845f;  // C^-0.5

// ---------------- weight prepack: 128 frags x 1 KiB ----------------
//  f in [ 0,32): A-frags of Wq^T (pre-scaled): id = h*8 + mt*4 + ks
//  f in [32,64): A-frags of Wk^T: id = 32 + h*8 + mt*4 + ks
//  f in [64,96): B-frags of Wv:   id = 64 + h*8 + nt*4 + ks
//  f in [96,128): B-frags of Wp^T: id = 96 + nt*4 + kt (kt = head slice of k)
__global__ void prepack(const float* __restrict__ Wq, const float* __restrict__ Wk,
                        const float* __restrict__ Wv, const float* __restrict__ Wp,
                        uint4* __restrict__ frags) {
  int tid = blockIdx.x * blockDim.x + threadIdx.x;   // 8192 threads
  int f = tid >> 6, lane = tid & 63, quad = lane >> 4, c16 = lane & 15;
  union { bf16 e[8]; uint4 v; } o;
  if (f < 64) {
    int isK = f >> 5, g = f & 31, h = g >> 3, mt = (g >> 2) & 1, ks = g & 3;
    const float* W = isK ? Wk : Wq;
    const float* src = W + h * 4096 + (ks * 32 + quad * 8) * 32 + mt * 16 + c16;
    float sc = isK ? 1.f : SCALE;
#pragma unroll
    for (int j = 0; j < 8; ++j) o.e[j] = (bf16)(src[j * 32] * sc);
  } else if (f < 96) {
    int g = f - 64, h = g >> 3, nt = (g >> 2) & 1, ks = g & 3;
    const float* src = Wv + h * 4096 + (ks * 32 + quad * 8) * 32 + nt * 16 + c16;
#pragma unroll
    for (int j = 0; j < 8; ++j) o.e[j] = (bf16)src[j * 32];
  } else {
    int g = f - 96, nt = g >> 2, kt = g & 3;
    const float* src = Wp + (nt * 16 + c16) * 128 + kt * 32 + quad * 8;
#pragma unroll
    for (int j = 0; j < 8; ++j) o.e[j] = (bf16)src[j];
  }
  frags[f * 64 + lane] = o.v;
}

__device__ __forceinline__ uint2 pack4(f32x4 a) {
  union { bf16 e[4]; uint2 u; } p;
#pragma unroll
  for (int r = 0; r < 4; ++r) p.e[r] = (bf16)a[r];
  return p.u;
}

// ---------------- fused MHA: 1 block = 1 batch, 4 waves, 1 wave = 1 head ----------------
// launch_bounds(256,3): ~168 VGPR budget -> NO spills (round-1 (256,4) capped at 128 and
// spilled the q/k/v fragment state to scratch: WRITE_SIZE 2.77x output).
// Phase 1 runs as 3 sequential passes (Q, K, V) so only one 32-reg weight set is live.
__global__ __launch_bounds__(256, 3) void mha4(
    const float* __restrict__ x, const bf16* __restrict__ fr,
    const float* __restrict__ bp, float* __restrict__ out) {
  __shared__ __align__(16) bf16 XO[128 * XS];      // x (bf16) -> later O[t][hd] -> Y f32 scratch
  __shared__ __align__(16) bf16 PS[4][16 * PSS];   // per-wave transpose slice (16 x 32 used)

  const int b = blockIdx.x, tid = threadIdx.x;
  const int w = tid >> 6, lane = tid & 63, quad = lane >> 4, c16 = lane & 15;
  const bf16x8* frv = (const bf16x8*)fr;
  bf16* ps = PS[w];

  // ---- phase 0: stage x as bf16 into XO (coalesced float4 loads) ----
  const float* xb = x + (size_t)b * 16384;
#pragma unroll
  for (int i = 0; i < 16; ++i) {
    int idx = tid + i * 256, row = idx >> 5, f4 = idx & 31;
    float4 a = *(const float4*)(xb + idx * 4);
    union { bf16 e[4]; uint2 u; } pk;
    pk.e[0] = (bf16)a.x; pk.e[1] = (bf16)a.y; pk.e[2] = (bf16)a.z; pk.e[3] = (bf16)a.w;
    *(uint2*)&XO[row * XS + f4 * 4] = pk.u;
  }
  __syncthreads();   // #1

  // ---- phase 1: projections for head h = w; end with qf/kf/vf in registers ----
  // qf[m]: lane = Q[t=m*16+c16][d=quad*8+j]      (B-frag of Q^T)
  // kf[nt]: lane = K[s=nt*16+c16][d=quad*8+j]    (A-frag)
  // vf[dt][kc]: lane = V^T[d=dt*16+c16][s=kc*32+quad*8+j] (A-frag)
  bf16x8 qf[8], kf[8], vf[2][4];
  // -- pass Q --
  {
    bf16x8 wq[2][4];
#pragma unroll
    for (int mt = 0; mt < 2; ++mt)
#pragma unroll
      for (int ks = 0; ks < 4; ++ks)
        wq[mt][ks] = frv[(w * 8 + mt * 4 + ks) * 64 + lane];
#pragma unroll
    for (int tt = 0; tt < 8; ++tt) {
      f32x4 a0 = {0,0,0,0}, a1 = {0,0,0,0};
#pragma unroll
      for (int ks = 0; ks < 4; ++ks) {
        bf16x8 xa = *(const bf16x8*)&XO[(tt * 16 + c16) * XS + ks * 32 + quad * 8];
        a0 = MFMA16(wq[0][ks], xa, a0);   // Q^T = Wq^T x^T : C row=d, col=t
        a1 = MFMA16(wq[1][ks], xa, a1);
      }
      *(uint2*)&ps[c16 * PSS + quad * 4] = pack4(a0);
      *(uint2*)&ps[c16 * PSS + 16 + quad * 4] = pack4(a1);
      qf[tt] = *(const bf16x8*)&ps[c16 * PSS + quad * 8];
    }
  }
  // -- pass K --
  {
    bf16x8 wk[2][4];
#pragma unroll
    for (int mt = 0; mt < 2; ++mt)
#pragma unroll
      for (int ks = 0; ks < 4; ++ks)
        wk[mt][ks] = frv[(32 + w * 8 + mt * 4 + ks) * 64 + lane];
#pragma unroll
    for (int tt = 0; tt < 8; ++tt) {
      f32x4 a0 = {0,0,0,0}, a1 = {0,0,0,0};
#pragma unroll
      for (int ks = 0; ks < 4; ++ks) {
        bf16x8 xa = *(const bf16x8*)&XO[(tt * 16 + c16) * XS + ks * 32 + quad * 8];
        a0 = MFMA16(wk[0][ks], xa, a0);
        a1 = MFMA16(wk[1][ks], xa, a1);
      }
      *(uint2*)&ps[c16 * PSS + quad * 4] = pack4(a0);
      *(uint2*)&ps[c16 * PSS + 16 + quad * 4] = pack4(a1);
      kf[tt] = *(const bf16x8*)&ps[c16 * PSS + quad * 8];
    }
  }
  // -- pass V --
  {
    bf16x8 wv[2][4];
#pragma unroll
    for (int nt = 0; nt < 2; ++nt)
#pragma unroll
      for (int ks = 0; ks < 4; ++ks)
        wv[nt][ks] = frv[(64 + w * 8 + nt * 4 + ks) * 64 + lane];
    uint2 vp[2][2];
#pragma unroll
    for (int tt = 0; tt < 8; ++tt) {
      f32x4 v0 = {0,0,0,0}, v1 = {0,0,0,0};
#pragma unroll
      for (int ks = 0; ks < 4; ++ks) {
        bf16x8 xa = *(const bf16x8*)&XO[(tt * 16 + c16) * XS + ks * 32 + quad * 8];
        v0 = MFMA16(xa, wv[0][ks], v0);   // V = x Wv : C row=s, col=d
        v1 = MFMA16(xa, wv[1][ks], v1);
      }
      vp[0][tt & 1] = pack4(v0);
      vp[1][tt & 1] = pack4(v1);
      if (tt & 1) {
        const int kc = tt >> 1;
#pragma unroll
        for (int dt = 0; dt < 2; ++dt) {
          *(uint2*)&ps[c16 * PSS + quad * 4] = vp[dt][0];       // [d=c16][s 0..15]
          *(uint2*)&ps[c16 * PSS + 16 + quad * 4] = vp[dt][1];  // [d=c16][s 16..31]
          vf[dt][kc] = *(const bf16x8*)&ps[c16 * PSS + quad * 8];
        }
      }
    }
  }
  __syncthreads();   // #2 — all x reads done; XO becomes O[t][hd]

  // ---- phase 2: attention, fully wave-independent ----
#pragma unroll
  for (int m = 0; m < 8; ++m) {
    f32x4 st[8];
#pragma unroll
    for (int nt = 0; nt < 8; ++nt) {
      if (nt <= m) {
        f32x4 z = {0,0,0,0};
        st[nt] = MFMA16(kf[nt], qf[m], z);   // S^T: lane col t = m*16+c16, rows s = nt*16+quad*4+r
      }
    }
    float mx = -1e30f;
#pragma unroll
    for (int nt = 0; nt < 8; ++nt) {
      if (nt < m) {
#pragma unroll
        for (int r = 0; r < 4; ++r) mx = fmaxf(mx, st[nt][r]);
      } else if (nt == m) {
#pragma unroll
        for (int r = 0; r < 4; ++r) {
          float v = (quad * 4 + r > c16) ? -1e30f : st[nt][r];
          st[nt][r] = v;
          mx = fmaxf(mx, v);
        }
      }
    }
    mx = fmaxf(mx, __shfl_xor(mx, 16));
    mx = fmaxf(mx, __shfl_xor(mx, 32));
    float sum = 0.f;
#pragma unroll
    for (int nt = 0; nt < 8; ++nt) {
      if (nt <= m) {
#pragma unroll
        for (int r = 0; r < 4; ++r) {
          float e = __expf(st[nt][r] - mx);
          st[nt][r] = e;
          sum += e;
        }
      }
    }
    sum += __shfl_xor(sum, 16);
    sum += __shfl_xor(sum, 32);
    const float inv = __builtin_amdgcn_rcpf(sum);

    f32x4 oa0 = {0,0,0,0}, oa1 = {0,0,0,0};
#pragma unroll
    for (int kc = 0; kc < 4; ++kc) {
      if (kc <= (m >> 1)) {
#pragma unroll
        for (int n2 = 0; n2 < 2; ++n2) {
          const int nt = kc * 2 + n2;
          uint2 p;
          if (nt <= m) p = pack4(st[nt]);
          else { p.x = 0u; p.y = 0u; }
          *(uint2*)&ps[c16 * PSS + n2 * 16 + quad * 4] = p;
        }
        bf16x8 pf = *(const bf16x8*)&ps[c16 * PSS + quad * 8];
        oa0 = MFMA16(vf[0][kc], pf, oa0);
        oa1 = MFMA16(vf[1][kc], pf, oa1);
      }
    }
    // stage O (normalized) into XO[t][hd] at this wave's column stripe
    union { bf16 e[4]; uint2 u; } q0, q1;
#pragma unroll
    for (int r = 0; r < 4; ++r) {
      q0.e[r] = (bf16)(oa0[r] * inv);
      q1.e[r] = (bf16)(oa1[r] * inv);
    }
    *(uint2*)&XO[(m * 16 + c16) * XS + w * 32 + quad * 4] = q0.u;
    *(uint2*)&XO[(m * 16 + c16) * XS + w * 32 + 16 + quad * 4] = q1.u;
  }
  __syncthreads();   // #3 — O complete

  // ---- phase 3: Y = O Wp^T + b ; wave w owns rows w*32..w*32+31 ----
  float bias[8];
#pragma unroll
  for (int nt = 0; nt < 8; ++nt) bias[nt] = bp[nt * 16 + c16];
  f32x4 yacc[2][8];
#pragma unroll
  for (int rb = 0; rb < 2; ++rb)
#pragma unroll
    for (int nt = 0; nt < 8; ++nt) yacc[rb][nt] = (f32x4){0,0,0,0};
#pragma unroll
  for (int rb = 0; rb < 2; ++rb) {
    bf16x8 of[4];
#pragma unroll
    for (int kt = 0; kt < 4; ++kt)
      of[kt] = *(const bf16x8*)&XO[(w * 32 + rb * 16 + c16) * XS + kt * 32 + quad * 8];
#pragma unroll
    for (int nt = 0; nt < 8; ++nt)
#pragma unroll
      for (int kt = 0; kt < 4; ++kt)
        yacc[rb][nt] = MFMA16(of[kt], frv[(96 + nt * 4 + kt) * 64 + lane], yacc[rb][nt]);
  }

  // ---- epilogue: per-wave LDS transpose -> full-line float4 stores ----
  float* YS = (float*)&XO[(w * 32) * XS];   // wave-private region, stride 132 f32, 16 rows
  float* ob = out + (size_t)b * 16384 + (w * 32) * 128;
#pragma unroll
  for (int p = 0; p < 2; ++p) {
#pragma unroll
    for (int nt = 0; nt < 8; ++nt)
#pragma unroll
      for (int r = 0; r < 4; ++r)
        YS[(quad * 4 + r) * 132 + nt * 16 + c16] = yacc[p][nt][r] + bias[nt];
#pragma unroll
    for (int si = 0; si < 8; ++si) {
      const int row = (lane >> 5) + si * 2;
      *(float4*)&ob[(p * 16 + row) * 128 + (lane & 31) * 4] =
          *(const float4*)&YS[row * 132 + (lane & 31) * 4];
    }
  }
}

extern "C" void kernel_launch(void* const* d_in, const int* in_sizes, int n_in,
                              void* d_out, int out_size, void* d_ws, size_t ws_size,
                              hipStream_t stream) {
  (void)in_sizes; (void)n_in; (void)out_size; (void)ws_size;
  const float* x  = (const float*)d_in[0];
  const float* Wq = (const float*)d_in[1];
  const float* Wk = (const float*)d_in[2];
  const float* Wv = (const float*)d_in[3];
  const float* Wp = (const float*)d_in[4];
  const float* bp = (const float*)d_in[5];
  bf16* frags = (bf16*)d_ws;   // 128 frags * 1 KiB = 128 KiB
  prepack<<<dim3(32), dim3(256), 0, stream>>>(Wq, Wk, Wv, Wp, (uint4*)frags);
  mha4<<<dim3(4096), dim3(256), 0, stream>>>(x, frags, bp, (float*)d_out);
}